// Round 2
// baseline (3396.041 us; speedup 1.0000x reference)
//
#include <hip/hip_runtime.h>
#include <math.h>

#define NPTS 4096
#define NB 2
#define K_TOTAL 12
#define BLOCK 256
#define TILE 128
#define NT (NPTS / TILE)   // 32 tile-blocks per dimension

// ws layout (floats):
//  [0..24)        sched: 12 x {eps, w}
//  [32..40)       Mbuf: per (pot,batch) running max of h
//  [48..56)       counters (unsigned): cross b0/b1, xx b0/b1, yy b0/b1
//  [64..)         P: 4 pots x NB x NPTS   (f_ba, g_ab, f_aa, g_bb)
//  [..)           V: exp(h - M) per source pot
//  [..)           S: row-sum accumulators per pot
#define SCHED_OFF 0
#define MBUF_OFF 32
#define CNT_OFF 48
#define P_OFF 64
#define POT_SZ (4 * NB * NPTS)
#define V_OFF (P_OFF + POT_SZ)
#define S_OFF (V_OFF + POT_SZ)

#if __has_builtin(__builtin_amdgcn_exp2f)
#define EXP2F __builtin_amdgcn_exp2f
#else
#define EXP2F exp2f
#endif
#if __has_builtin(__builtin_amdgcn_logf)
#define LOG2F __builtin_amdgcn_logf
#else
#define LOG2F log2f
#endif
#if __has_builtin(__builtin_amdgcn_sqrtf)
#define FSQRTF __builtin_amdgcn_sqrtf
#else
#define FSQRTF sqrtf
#endif

#define BASE_LOGW -8.31776616671934f  // -log(4096), N==M
#define LOG2E 1.4426950408889634f
#define LN2 0.69314718055994531f

// ---------------------------------------------------------------------------
// Kernel A (grid=64): block 0 computes diameter (f32, matching numpy) +
// eps schedule (f64, matching np.arange/np.exp) + Mbuf + counters;
// blocks 1..63 zero P/S and set V=1.
// ---------------------------------------------------------------------------
__global__ __launch_bounds__(BLOCK) void k_init(
    const float2* __restrict__ x, const float2* __restrict__ y, float* ws)
{
  const int tid = threadIdx.x;
  const int bid = blockIdx.x;

  if (bid > 0) {
    for (int i = (bid - 1) * BLOCK + tid; i < POT_SZ; i += 63 * BLOCK) {
      ws[P_OFF + i] = 0.0f;
      ws[S_OFF + i] = 0.0f;
      ws[V_OFF + i] = 1.0f;
    }
    return;
  }

  if (tid < 8) ws[MBUF_OFF + tid] = BASE_LOGW;
  if (tid < 8) ((unsigned*)ws)[CNT_OFF + tid] = 0u;

  float mnx = 1e30f, mny = 1e30f, mxx = -1e30f, mxy = -1e30f;
  for (int i = tid; i < NB * NPTS; i += BLOCK) {
    float2 p = x[i];
    mnx = fminf(mnx, p.x); mxx = fmaxf(mxx, p.x);
    mny = fminf(mny, p.y); mxy = fmaxf(mxy, p.y);
    float2 q = y[i];
    mnx = fminf(mnx, q.x); mxx = fmaxf(mxx, q.x);
    mny = fminf(mny, q.y); mxy = fmaxf(mxy, q.y);
  }
  for (int o = 32; o; o >>= 1) {
    mnx = fminf(mnx, __shfl_xor(mnx, o, 64));
    mxx = fmaxf(mxx, __shfl_xor(mxx, o, 64));
    mny = fminf(mny, __shfl_xor(mny, o, 64));
    mxy = fmaxf(mxy, __shfl_xor(mxy, o, 64));
  }
  __shared__ float r[4][4];
  const int wave = tid >> 6, lane = tid & 63;
  if (lane == 0) { r[0][wave] = mnx; r[1][wave] = mxx; r[2][wave] = mny; r[3][wave] = mxy; }
  __syncthreads();
  if (tid == 0) {
    mnx = fminf(fminf(r[0][0], r[0][1]), fminf(r[0][2], r[0][3]));
    mxx = fmaxf(fmaxf(r[1][0], r[1][1]), fmaxf(r[1][2], r[1][3]));
    mny = fminf(fminf(r[2][0], r[2][1]), fminf(r[2][2], r[2][3]));
    mxy = fmaxf(fmaxf(r[3][0], r[3][1]), fmaxf(r[3][2], r[3][3]));
    float rx = mxx - mnx, ry = mxy - mny;
    float dia = sqrtf(rx * rx + ry * ry);

    double a = log((double)dia);
    double stop = log(0.05);
    double stp = log(0.5);
    int cnt = (int)ceil((stop - a) / stp);  // data: cnt == 8
    if (cnt < 0) cnt = 0;
    if (cnt > K_TOTAL - 4) cnt = K_TOTAL - 4;

    float* sch = ws + SCHED_OFF;
    sch[0] = dia; sch[1] = 0.0f;   // init: direct assign at eps=diameter
    sch[2] = dia; sch[3] = 0.5f;   // loop over eps_list, w=0.5
    for (int k = 0; k < cnt; k++) {
      sch[2 * (2 + k)] = (float)exp(a + (double)k * stp);
      sch[2 * (2 + k) + 1] = 0.5f;
    }
    sch[2 * (2 + cnt)] = 0.05f; sch[2 * (2 + cnt) + 1] = 0.5f;
    for (int s = 3 + cnt; s < K_TOTAL - 1; s++) { sch[2 * s] = 0.05f; sch[2 * s + 1] = 1.0f; }
    sch[2 * (K_TOTAL - 1)] = 0.05f; sch[2 * (K_TOTAL - 1) + 1] = 0.0f;  // final extrapolation
  }
}

// ---------------------------------------------------------------------------
// Fused per-(pot,batch) combine: finalize f from S, mix with w, write P;
// build next step's V = exp(h - Mnew); zero S. Runs in the LAST k_tiles
// block (per counter) after a release/acquire handshake.
// ---------------------------------------------------------------------------
__device__ __forceinline__ void combine_pb(float* __restrict__ ws, int pb, int stepi)
{
  const int tid = threadIdx.x;
  const float eps = ws[SCHED_OFF + 2 * stepi];
  const float w = ws[SCHED_OFF + 2 * stepi + 1];
  int ni = stepi + 1; if (ni > K_TOTAL - 1) ni = K_TOTAL - 1;
  const float inv_eps_n = 1.0f / ws[SCHED_OFF + 2 * ni];
  const float Mh = ws[MBUF_OFF + pb];

  float* Pp = ws + P_OFF + pb * NPTS;
  float* Vp = ws + V_OFF + pb * NPTS;
  float* Sp = ws + S_OFF + pb * NPTS;

  float h[16];
  float lmax = -1e30f;
#pragma unroll
  for (int q = 0; q < 16; q++) {
    const int r = q * BLOCK + tid;
    float s = fmaxf(Sp[r], 1e-37f);
    float ft = -eps * fmaf(LN2, LOG2F(s), Mh);
    float fo = Pp[r];
    float fn = (w >= 1.0f) ? fo : fmaf(w, fo, (1.0f - w) * ft);
    Pp[r] = fn;
    Sp[r] = 0.0f;
    h[q] = fmaf(fn, inv_eps_n, BASE_LOGW);
    lmax = fmaxf(lmax, h[q]);
  }
  for (int o = 32; o; o >>= 1) lmax = fmaxf(lmax, __shfl_xor(lmax, o, 64));
  __shared__ float red[4];
  if ((tid & 63) == 0) red[tid >> 6] = lmax;
  __syncthreads();
  const float M = fmaxf(fmaxf(red[0], red[1]), fmaxf(red[2], red[3]));
  __syncthreads();  // red may be reused by a second combine_pb call
#pragma unroll
  for (int q = 0; q < 16; q++) {
    const int r = q * BLOCK + tid;
    Vp[r] = EXP2F((h[q] - M) * LOG2E);
  }
  if (tid == 0) ws[MBUF_OFF + pb] = M;
}

// ---------------------------------------------------------------------------
// Kernel B: K-tile sweep. Each block owns a 128x128 tile of one cost matrix.
// Coordinates are pre-scaled by sc = log2e/eps at LDS staging, so the inner
// loop is: d2 = dx*dx+dy*dy (scaled), K = exp2(-sqrt(d2)) -- 6 VALU + 2
// trans per entry, no clamp, no per-entry eps multiply.
//  - cross tiles (C_xy): rows feed S0 (f_ba) via V1, cols feed S1 (g_ab)
//    via V0 -- one sqrt+exp serves two potentials.
//  - self tiles (C_xx / C_yy, symmetric): only ti<=tj computed.
// blocks: [0, 2048) cross; [2048, 6144) self (ti>tj blocks exit early).
// The last block to finish a matrix (atomic counter) runs the combine for
// its potential(s) -- no separate k_combine kernel, no inter-step drain.
// ---------------------------------------------------------------------------
__global__ __launch_bounds__(BLOCK, 4) void k_tiles(
    const float2* __restrict__ xpts, const float2* __restrict__ ypts,
    float* __restrict__ ws, int stepi)
{
  __shared__ float rXs[TILE], rYs[TILE], rVs[TILE];
  __shared__ float cXs[TILE], cYs[TILE], cVs[TILE];
  __shared__ float rowPart[16][129];  // stride 129: write bank = tx+8*(lane>>4)+q -> <=2-way
  __shared__ float colPart[16][129];  // stride 129: 4-way (was 8-way at 132)
  __shared__ unsigned sLast;

  const int tid = threadIdx.x;
  const int id = blockIdx.x;

  const float2* rowp; const float2* colp;
  const float* vrow; const float* vcol;
  float* srow; float* scol;
  int ti, tj, cb, cmat;
  bool dual, isCross;

  if (id < NB * NT * NT) {
    const int b = id >> 10;
    const int t = id & (NT * NT - 1);
    ti = t >> 5; tj = t & (NT - 1);
    rowp = xpts + b * NPTS; colp = ypts + b * NPTS;
    vrow = ws + V_OFF + (0 * NB + b) * NPTS;  // V built from P0=f_ba
    vcol = ws + V_OFF + (1 * NB + b) * NPTS;  // V built from P1=g_ab
    srow = ws + S_OFF + (0 * NB + b) * NPTS;  // row sums -> new f_ba
    scol = ws + S_OFF + (1 * NB + b) * NPTS;  // col sums -> new g_ab
    dual = true; isCross = true; cb = b; cmat = 0;
  } else {
    const int id2 = id - NB * NT * NT;
    const int mat = id2 >> 11;      // 0: C_xx, 1: C_yy  (NB*NT*NT == 2048)
    const int t2 = id2 & 2047;
    const int b = t2 >> 10;
    const int t = t2 & 1023;
    ti = t >> 5; tj = t & 31;
    if (ti > tj) return;            // symmetric: upper triangle only
    const float2* pts = mat ? ypts : xpts;
    rowp = pts + b * NPTS; colp = rowp;
    const int p = 2 + mat;
    vrow = ws + V_OFF + (p * NB + b) * NPTS;
    vcol = vrow;
    srow = ws + S_OFF + (p * NB + b) * NPTS;
    scol = srow;
    dual = (ti != tj);              // diagonal tile: row sums only
    isCross = false; cb = b; cmat = mat;
  }

  const float eps = ws[SCHED_OFF + 2 * stepi];
  const float sc = LOG2E / eps;     // pre-scale coords: exp2(-sqrt(d2*sc^2)) = e^{-d/eps}

  if (tid < TILE) {
    float2 pr = rowp[ti * TILE + tid];
    rXs[tid] = pr.x * sc; rYs[tid] = pr.y * sc;
    rVs[tid] = vrow[ti * TILE + tid];
  } else {
    const int k = tid - TILE;
    float2 pc = colp[tj * TILE + k];
    cXs[k] = pc.x * sc; cYs[k] = pc.y * sc;
    cVs[k] = vcol[tj * TILE + k];
  }
  __syncthreads();

  const int tx = tid & 15, ty = tid >> 4;
  float rx[8], ry[8], rv[8], cx[8], cy[8], cv[8], racc[8], cacc[8];
#pragma unroll
  for (int q = 0; q < 8; q++) {
    rx[q] = rXs[ty * 8 + q]; ry[q] = rYs[ty * 8 + q]; rv[q] = rVs[ty * 8 + q];
    cx[q] = cXs[tx * 8 + q]; cy[q] = cYs[tx * 8 + q]; cv[q] = cVs[tx * 8 + q];
    racc[q] = 0.0f; cacc[q] = 0.0f;
  }

#pragma unroll
  for (int q = 0; q < 8; q++) {
#pragma unroll
    for (int p = 0; p < 8; p++) {
      float dx = rx[q] - cx[p];
      float dy = ry[q] - cy[p];
      float t = FSQRTF(fmaf(dx, dx, dy * dy));  // d2 >= 0 exactly (diff form)
      float K = EXP2F(-t);                      // neg is a free src modifier
      racc[q] = fmaf(K, cv[p], racc[q]);
      cacc[p] = fmaf(K, rv[q], cacc[p]);
    }
  }

#pragma unroll
  for (int q = 0; q < 8; q++) {
    rowPart[tx][ty * 8 + q] = racc[q];
    colPart[ty][tx * 8 + q] = cacc[q];
  }
  __syncthreads();

  if (tid < TILE) {
    float s = 0.0f;
#pragma unroll
    for (int t = 0; t < 16; t++) s += rowPart[t][tid];
    atomicAdd(&srow[ti * TILE + tid], s);
  } else if (dual) {
    const int k = tid - TILE;
    float s = 0.0f;
#pragma unroll
    for (int t = 0; t < 16; t++) s += colPart[t][k];
    atomicAdd(&scol[tj * TILE + k], s);
  }

  // ---- fused tail combine: last finishing block per matrix does it ----
  __threadfence();                  // release our S atomics (device scope)
  if (tid == 0) {
    unsigned* cnt = (unsigned*)ws + CNT_OFF;
    int ci; unsigned tot;
    if (isCross) { ci = cb; tot = NT * NT; }
    else { ci = 2 + cmat * 2 + cb; tot = (NT * (NT + 1)) / 2; }
    unsigned old = atomicAdd(&cnt[ci], 1u);
    unsigned last = (old == tot - 1u) ? 1u : 0u;
    if (last) cnt[ci] = 0u;         // reset for next step (all contributors done)
    sLast = last;
  }
  __syncthreads();
  if (sLast == 0u) return;
  __threadfence();                  // acquire: see all blocks' S atomics

  if (isCross) {
    combine_pb(ws, 0 * NB + cb, stepi);   // f_ba
    combine_pb(ws, 1 * NB + cb, stepi);   // g_ab
  } else {
    combine_pb(ws, (2 + cmat) * NB + cb, stepi);  // f_aa / g_bb
  }
}

// ---------------------------------------------------------------------------
// Kernel C: out = mean_b [ (1/N) sum(f_ba - f_aa) + (1/M) sum(g_ab - g_bb) ]
// ---------------------------------------------------------------------------
__global__ __launch_bounds__(1024) void k_reduce(
    const float* __restrict__ pot, float* __restrict__ out)
{
  const int tid = threadIdx.x;
  double acc = 0.0;
  for (int i = tid; i < POT_SZ; i += 1024) {
    double v = (double)pot[i];
    acc += (i < 2 * NB * NPTS) ? v : -v;  // +f_ba +g_ab -f_aa -g_bb
  }
  for (int o = 32; o; o >>= 1) acc += __shfl_xor(acc, o, 64);
  __shared__ double rd[16];
  const int wave = tid >> 6, lane = tid & 63;
  if (lane == 0) rd[wave] = acc;
  __syncthreads();
  if (tid == 0) {
    double s = 0.0;
#pragma unroll
    for (int i = 0; i < 16; i++) s += rd[i];
    out[0] = (float)(s / (double)(NB * NPTS));
  }
}

extern "C" void kernel_launch(void* const* d_in, const int* in_sizes, int n_in,
                              void* d_out, int out_size, void* d_ws, size_t ws_size,
                              hipStream_t stream)
{
  const float2* x = (const float2*)d_in[0];  // pre (2,4096,2)
  const float2* y = (const float2*)d_in[1];  // gt  (2,4096,2)
  float* ws = (float*)d_ws;

  k_init<<<64, BLOCK, 0, stream>>>(x, y, ws);

  const int nblocks = NB * NT * NT + 2 * NB * NT * NT;  // 2048 cross + 4096 self
  for (int s = 0; s < K_TOTAL; s++) {
    k_tiles<<<nblocks, BLOCK, 0, stream>>>(x, y, ws, s);
  }
  k_reduce<<<1, 1024, 0, stream>>>(ws + P_OFF, (float*)d_out);
}

// Round 3
// 664.592 us; speedup vs baseline: 5.1100x; 5.1100x over previous
//
#include <hip/hip_runtime.h>
#include <math.h>

#define NPTS 4096
#define NB 2
#define K_TOTAL 12
#define BLOCK 256
#define TILE 128
#define NT (NPTS / TILE)   // 32 tile-blocks per dimension

// ws layout (floats / 4B words):
//  [0..24)    sched: 12 x {eps, w}
//  [32..48)   Mbuf (unsigned, monotone-encoded float max): 2 slots x 8 (pot,batch)
//  [64..)     P: 4 pots x NB x NPTS   (f_ba, g_ab, f_aa, g_bb)
//  [..)       S: row-sum accumulators per pot
#define SCHED_OFF 0
#define MBUF_OFF 32
#define P_OFF 64
#define POT_SZ (4 * NB * NPTS)
#define S_OFF (P_OFF + POT_SZ)

#if __has_builtin(__builtin_amdgcn_exp2f)
#define EXP2F __builtin_amdgcn_exp2f
#else
#define EXP2F exp2f
#endif
#if __has_builtin(__builtin_amdgcn_logf)
#define LOG2F __builtin_amdgcn_logf
#else
#define LOG2F log2f
#endif
#if __has_builtin(__builtin_amdgcn_sqrtf)
#define FSQRTF __builtin_amdgcn_sqrtf
#else
#define FSQRTF sqrtf
#endif

#define BASE_LOGW -8.31776616671934f  // -log(4096), N==M
#define LOG2E 1.4426950408889634f
#define LN2 0.69314718055994531f

// monotone float<->uint encoding so unsigned atomicMax == float max
__device__ __forceinline__ unsigned encf(float f) {
  unsigned u = __float_as_uint(f);
  return (u & 0x80000000u) ? ~u : (u | 0x80000000u);
}
__device__ __forceinline__ float decf(unsigned k) {
  return __uint_as_float((k & 0x80000000u) ? (k ^ 0x80000000u) : ~k);
}

// ---------------------------------------------------------------------------
// Kernel A (grid=64): block 0 computes diameter (f32, matching numpy) +
// eps schedule (f64, matching np.arange/np.exp) + Mbuf slots;
// blocks 1..63 zero P and S.
// ---------------------------------------------------------------------------
__global__ __launch_bounds__(BLOCK) void k_init(
    const float2* __restrict__ x, const float2* __restrict__ y, float* ws)
{
  const int tid = threadIdx.x;
  const int bid = blockIdx.x;

  if (bid > 0) {
    for (int i = (bid - 1) * BLOCK + tid; i < POT_SZ; i += 63 * BLOCK) {
      ws[P_OFF + i] = 0.0f;
      ws[S_OFF + i] = 0.0f;
    }
    return;
  }

  if (tid < 8) {
    unsigned* MB = (unsigned*)ws + MBUF_OFF;
    MB[8 + tid] = encf(BASE_LOGW);  // slot 1: M_{-1} (P=0 -> h=logw -> V=1)
    MB[tid] = encf(-1e30f);         // slot 0: target of step-0 combine
  }

  float mnx = 1e30f, mny = 1e30f, mxx = -1e30f, mxy = -1e30f;
  for (int i = tid; i < NB * NPTS; i += BLOCK) {
    float2 p = x[i];
    mnx = fminf(mnx, p.x); mxx = fmaxf(mxx, p.x);
    mny = fminf(mny, p.y); mxy = fmaxf(mxy, p.y);
    float2 q = y[i];
    mnx = fminf(mnx, q.x); mxx = fmaxf(mxx, q.x);
    mny = fminf(mny, q.y); mxy = fmaxf(mxy, q.y);
  }
  for (int o = 32; o; o >>= 1) {
    mnx = fminf(mnx, __shfl_xor(mnx, o, 64));
    mxx = fmaxf(mxx, __shfl_xor(mxx, o, 64));
    mny = fminf(mny, __shfl_xor(mny, o, 64));
    mxy = fmaxf(mxy, __shfl_xor(mxy, o, 64));
  }
  __shared__ float r[4][4];
  const int wave = tid >> 6, lane = tid & 63;
  if (lane == 0) { r[0][wave] = mnx; r[1][wave] = mxx; r[2][wave] = mny; r[3][wave] = mxy; }
  __syncthreads();
  if (tid == 0) {
    mnx = fminf(fminf(r[0][0], r[0][1]), fminf(r[0][2], r[0][3]));
    mxx = fmaxf(fmaxf(r[1][0], r[1][1]), fmaxf(r[1][2], r[1][3]));
    mny = fminf(fminf(r[2][0], r[2][1]), fminf(r[2][2], r[2][3]));
    mxy = fmaxf(fmaxf(r[3][0], r[3][1]), fmaxf(r[3][2], r[3][3]));
    float rx = mxx - mnx, ry = mxy - mny;
    float dia = sqrtf(rx * rx + ry * ry);

    double a = log((double)dia);
    double stop = log(0.05);
    double stp = log(0.5);
    int cnt = (int)ceil((stop - a) / stp);  // data: cnt == 8
    if (cnt < 0) cnt = 0;
    if (cnt > K_TOTAL - 4) cnt = K_TOTAL - 4;

    float* sch = ws + SCHED_OFF;
    sch[0] = dia; sch[1] = 0.0f;   // init: direct assign at eps=diameter
    sch[2] = dia; sch[3] = 0.5f;   // loop over eps_list, w=0.5
    for (int k = 0; k < cnt; k++) {
      sch[2 * (2 + k)] = (float)exp(a + (double)k * stp);
      sch[2 * (2 + k) + 1] = 0.5f;
    }
    sch[2 * (2 + cnt)] = 0.05f; sch[2 * (2 + cnt) + 1] = 0.5f;
    for (int s = 3 + cnt; s < K_TOTAL - 1; s++) { sch[2 * s] = 0.05f; sch[2 * s + 1] = 1.0f; }
    sch[2 * (K_TOTAL - 1)] = 0.05f; sch[2 * (K_TOTAL - 1) + 1] = 0.0f;  // final extrapolation
  }
}

// ---------------------------------------------------------------------------
// Kernel B: K-tile sweep. Each block owns a 128x128 tile of one cost matrix.
// V is built ON THE FLY at staging from P + M (no V array): 3 extra ops per
// staged element, amortized over 128 inner entries. Coordinates pre-scaled by
// sc = log2e/eps, so inner entry = 2 sub, mul+fma, sqrt, exp2, 2 acc-fma.
// Epilogue: in-wave shuffle reductions (rows: xor 1/2/4/8 in 16-lane groups;
// cols: xor 16/32 + tiny 4x128 LDS combine) -- no 16x129 transpose buffers.
// blocks: [0, 2048) cross; [2048, 6144) self (ti>tj exit early).
// Block 0 also resets this step's Mbuf slot for k_combine's atomicMax.
// ---------------------------------------------------------------------------
__global__ __launch_bounds__(BLOCK, 4) void k_tiles(
    const float2* __restrict__ xpts, const float2* __restrict__ ypts,
    float* __restrict__ ws, int stepi)
{
  __shared__ float rXs[TILE], rYs[TILE], rVs[TILE];
  __shared__ float cXs[144], cYs[144], cVs[144];  // padded: idx + idx/8
  __shared__ float colPart[4][TILE];

  const int tid = threadIdx.x;
  const int id = blockIdx.x;

  const float2* rowp; const float2* colp;
  const float* prow; const float* pcol;
  float* srow; float* scol;
  int ti, tj, pbr, pbc;
  bool dual;

  if (id < NB * NT * NT) {
    const int b = id >> 10;
    const int t = id & (NT * NT - 1);
    ti = t >> 5; tj = t & (NT - 1);
    rowp = xpts + b * NPTS; colp = ypts + b * NPTS;
    prow = ws + P_OFF + (0 * NB + b) * NPTS;  // P0 = f_ba drives row-side V
    pcol = ws + P_OFF + (1 * NB + b) * NPTS;  // P1 = g_ab drives col-side V
    srow = ws + S_OFF + (0 * NB + b) * NPTS;  // row sums -> new f_ba
    scol = ws + S_OFF + (1 * NB + b) * NPTS;  // col sums -> new g_ab
    pbr = 0 * NB + b; pbc = 1 * NB + b;
    dual = true;
  } else {
    const int id2 = id - NB * NT * NT;
    const int mat = id2 >> 11;      // 0: C_xx, 1: C_yy
    const int t2 = id2 & 2047;
    const int b = t2 >> 10;
    const int t = t2 & 1023;
    ti = t >> 5; tj = t & 31;
    if (ti > tj) return;            // symmetric: upper triangle only
    const float2* pts = mat ? ypts : xpts;
    rowp = pts + b * NPTS; colp = rowp;
    const int p = 2 + mat;
    prow = ws + P_OFF + (p * NB + b) * NPTS; pcol = prow;
    srow = ws + S_OFF + (p * NB + b) * NPTS; scol = srow;
    pbr = p * NB + b; pbc = pbr;
    dual = (ti != tj);              // diagonal tile: row sums only
  }

  const float eps = ws[SCHED_OFF + 2 * stepi];
  const float sc = LOG2E / eps;     // exp2(-sqrt(d2_scaled)) = e^{-d/eps}
  const float inv_eps = 1.0f / eps; // h = logw + P/eps (this step's V)
  const unsigned* MB = (const unsigned*)ws + MBUF_OFF + 8 * ((stepi + 1) & 1);

  if (id == 0 && tid < 8)           // reset the OTHER slot for this step's combine
    ((unsigned*)ws)[MBUF_OFF + 8 * (stepi & 1) + tid] = encf(-1e30f);

  if (tid < TILE) {
    const int r = ti * TILE + tid;
    float2 pr = rowp[r];
    float h = fmaf(prow[r], inv_eps, BASE_LOGW);
    rXs[tid] = pr.x * sc; rYs[tid] = pr.y * sc;
    rVs[tid] = EXP2F((h - decf(MB[pbr])) * LOG2E);
  } else {
    const int k = tid - TILE;
    const int r = tj * TILE + k;
    float2 pc = colp[r];
    float h = fmaf(pcol[r], inv_eps, BASE_LOGW);
    const int kk = k + (k >> 3);    // pad to break 4-way preload conflict
    cXs[kk] = pc.x * sc; cYs[kk] = pc.y * sc;
    cVs[kk] = EXP2F((h - decf(MB[pbc])) * LOG2E);
  }
  __syncthreads();

  const int tx = tid & 15, ty = tid >> 4;
  float rx[8], ry[8], rv[8], cx[8], cy[8], cv[8], racc[8], cacc[8];
#pragma unroll
  for (int q = 0; q < 8; q++) {
    rx[q] = rXs[ty * 8 + q]; ry[q] = rYs[ty * 8 + q]; rv[q] = rVs[ty * 8 + q];
    const int ci = tx * 9 + q;      // (tx*8+q) padded
    cx[q] = cXs[ci]; cy[q] = cYs[ci]; cv[q] = cVs[ci];
    racc[q] = 0.0f; cacc[q] = 0.0f;
  }

#pragma unroll
  for (int q = 0; q < 8; q++) {
#pragma unroll
    for (int p = 0; p < 8; p++) {
      float dx = rx[q] - cx[p];
      float dy = ry[q] - cy[p];
      float t = FSQRTF(fmaf(dx, dx, dy * dy));
      float K = EXP2F(-t);          // neg is a free src modifier
      racc[q] = fmaf(K, cv[p], racc[q]);
      cacc[p] = fmaf(K, rv[q], cacc[p]);
    }
  }

  // rows: threads sharing ty are lanes (ty&3)*16 .. +15 of a wave -> xor 1/2/4/8
#pragma unroll
  for (int q = 0; q < 8; q++) {
    float v = racc[q];
    v += __shfl_xor(v, 1, 64);
    v += __shfl_xor(v, 2, 64);
    v += __shfl_xor(v, 4, 64);
    v += __shfl_xor(v, 8, 64);
    racc[q] = v;
  }
  // cols: threads sharing tx are lanes tx, tx+16, tx+32, tx+48 -> xor 16/32
#pragma unroll
  for (int q = 0; q < 8; q++) {
    float v = cacc[q];
    v += __shfl_xor(v, 16, 64);
    v += __shfl_xor(v, 32, 64);
    cacc[q] = v;
  }

  if ((tid & 15) == 0) {            // one lane per ty: full row sums (8 rows)
    const int row0 = ty * 8;
#pragma unroll
    for (int q = 0; q < 8; q++) atomicAdd(&srow[ti * TILE + row0 + q], racc[q]);
  }
  if ((tid & 63) < 16) {            // one lane per (wave, tx): wave's col partials
    const int w = tid >> 6;
#pragma unroll
    for (int q = 0; q < 8; q++) colPart[w][tx * 8 + q] = cacc[q];
  }
  __syncthreads();
  if (dual && tid < TILE) {
    float s = (colPart[0][tid] + colPart[1][tid]) + (colPart[2][tid] + colPart[3][tid]);
    atomicAdd(&scol[tj * TILE + tid], s);
  }
}

// ---------------------------------------------------------------------------
// Kernel C (grid=32: 8 pb x 4 chunks): finalize f from S (+Mh), mix with w,
// write P in place, zero S, and atomicMax the new h-max into this step's
// Mbuf slot. V is NOT materialized (k_tiles builds it at staging).
// ---------------------------------------------------------------------------
__global__ __launch_bounds__(BLOCK) void k_combine(float* __restrict__ ws, int stepi)
{
  const int bid = blockIdx.x;
  const int pb = bid >> 2, chunk = bid & 3;
  const int tid = threadIdx.x;

  const float eps = ws[SCHED_OFF + 2 * stepi];
  const float w = ws[SCHED_OFF + 2 * stepi + 1];
  int ni = stepi + 1; if (ni > K_TOTAL - 1) ni = K_TOTAL - 1;
  const float inv_eps_n = 1.0f / ws[SCHED_OFF + 2 * ni];
  unsigned* MB = (unsigned*)ws + MBUF_OFF;
  const float Mh = decf(MB[8 * ((stepi + 1) & 1) + pb]);  // M used in this step's V

  float* Pp = ws + P_OFF + pb * NPTS + chunk * 1024;
  float* Sp = ws + S_OFF + pb * NPTS + chunk * 1024;

  float lmax = -1e30f;
#pragma unroll
  for (int q = 0; q < 4; q++) {
    const int r = q * BLOCK + tid;
    float s = fmaxf(Sp[r], 1e-37f);
    float ft = -eps * fmaf(LN2, LOG2F(s), Mh);
    float fo = Pp[r];
    float fn = (w >= 1.0f) ? fo : fmaf(w, fo, (1.0f - w) * ft);
    Pp[r] = fn;
    Sp[r] = 0.0f;
    lmax = fmaxf(lmax, fmaf(fn, inv_eps_n, BASE_LOGW));  // h for next step
  }
  for (int o = 32; o; o >>= 1) lmax = fmaxf(lmax, __shfl_xor(lmax, o, 64));
  __shared__ float red[4];
  if ((tid & 63) == 0) red[tid >> 6] = lmax;
  __syncthreads();
  if (tid == 0) {
    float M = fmaxf(fmaxf(red[0], red[1]), fmaxf(red[2], red[3]));
    atomicMax(&MB[8 * (stepi & 1) + pb], encf(M));
  }
}

// ---------------------------------------------------------------------------
// Kernel D: out = mean_b [ (1/N) sum(f_ba - f_aa) + (1/M) sum(g_ab - g_bb) ]
// ---------------------------------------------------------------------------
__global__ __launch_bounds__(1024) void k_reduce(
    const float* __restrict__ pot, float* __restrict__ out)
{
  const int tid = threadIdx.x;
  double acc = 0.0;
  for (int i = tid; i < POT_SZ; i += 1024) {
    double v = (double)pot[i];
    acc += (i < 2 * NB * NPTS) ? v : -v;  // +f_ba +g_ab -f_aa -g_bb
  }
  for (int o = 32; o; o >>= 1) acc += __shfl_xor(acc, o, 64);
  __shared__ double rd[16];
  const int wave = tid >> 6, lane = tid & 63;
  if (lane == 0) rd[wave] = acc;
  __syncthreads();
  if (tid == 0) {
    double s = 0.0;
#pragma unroll
    for (int i = 0; i < 16; i++) s += rd[i];
    out[0] = (float)(s / (double)(NB * NPTS));
  }
}

extern "C" void kernel_launch(void* const* d_in, const int* in_sizes, int n_in,
                              void* d_out, int out_size, void* d_ws, size_t ws_size,
                              hipStream_t stream)
{
  const float2* x = (const float2*)d_in[0];  // pre (2,4096,2)
  const float2* y = (const float2*)d_in[1];  // gt  (2,4096,2)
  float* ws = (float*)d_ws;

  k_init<<<64, BLOCK, 0, stream>>>(x, y, ws);

  const int nblocks = NB * NT * NT + 2 * NB * NT * NT;  // 2048 cross + 4096 self
  for (int s = 0; s < K_TOTAL; s++) {
    k_tiles<<<nblocks, BLOCK, 0, stream>>>(x, y, ws, s);
    k_combine<<<32, BLOCK, 0, stream>>>(ws, s);
  }
  k_reduce<<<1, 1024, 0, stream>>>(ws + P_OFF, (float*)d_out);
}